// Round 4
// baseline (33.985 us; speedup 1.0000x reference)
//
#include <hip/hip_runtime.h>
#include <hip/hip_bf16.h>

#define NB 32
#define TS 300
#define NBATCH 16384
#define DTF (1.0f/300.0f)
#define A_ELEMS (NBATCH*2*TS)   /* 9,830,400 */

typedef __attribute__((ext_vector_type(8))) short bf16x8;
typedef __attribute__((ext_vector_type(4))) float f32x4;

static __device__ __forceinline__ ushort f2bf(float f) {
    union { __hip_bfloat16 h; ushort u; } cv;
    cv.h = __float2bfloat16(f);
    return cv.u;
}
static __device__ __forceinline__ float rdlane(float v, int lane) {
    return __int_as_float(__builtin_amdgcn_readlane(__float_as_int(v), lane));
}

// Fully fused: per block = 32 batches' heads + 64 channels' rollout.
// Phase 0: weights->LDS (swizzled), phi table->LDS (bf16, XOR slot swizzle).
// Phase 1: MLP heads -> w/params in LDS (no HBM round-trip).
// Phase 2: rollout. MFMA forcing; v_permlane16/32_swap gives every lane the
// full 16-step force column -> full recurrence per lane (no partial-state
// split). LDS tile only for store transpose: 1 ds_write_b128 + 1
// ds_read_b128 per chunk; 4 consecutive lanes store 64B contiguous.
__global__ __launch_bounds__(256) void k_fused(
    const float* __restrict__ state,
    const float* __restrict__ fc1_w, const float* __restrict__ fc1_b,
    const float* __restrict__ fc2m_w, const float* __restrict__ fc2m_b,
    const float* __restrict__ sig_w, const float* __restrict__ sig_b,
    const float* __restrict__ val_w, const float* __restrict__ val_b,
    const float* __restrict__ dmp_c, const float* __restrict__ dmp_s2,
    float* __restrict__ sig_out, float* __restrict__ a_out,
    float* __restrict__ v_out)
{
    __shared__ ushort phis[304*NB];     // 19456 B, slot^(t&3) swizzle
    __shared__ float  wlds[70*64];      // 17920 B, quad-XOR swizzled rows
    __shared__ float  f1[64*4];         // 1024 B
    __shared__ ushort wloc[64*NB];      // 4096 B  per-channel w (bf16)
    __shared__ float4 ppl[64];          // 1024 B  {goal,kfac,az,v}
    __shared__ float4 xt[4][16][5];     // 5120 B  store-transpose (pad 5)

    const int tid = threadIdx.x;
    const int wv  = tid >> 6;
    const int j   = tid & 63;

    // ---- phase 0a: weights -> LDS ----
    for (int i = tid; i < 70*64; i += 256) {
        const int row = i >> 6, col = i & 63;
        float v;
        if (row < 66)      v = fc2m_w[i];
        else if (row < 68) v = sig_w[(row-66)*64 + col];
        else               v = val_w[(row-68)*64 + col];
        const int q = col >> 2, e = col & 3;
        wlds[row*64 + (((q ^ (row & 15)) << 2) | e)] = v;
    }
    if (tid < 64) {
        f1[tid*4+0] = fc1_w[tid*3+0];
        f1[tid*4+1] = fc1_w[tid*3+1];
        f1[tid*4+2] = fc1_w[tid*3+2];
        f1[tid*4+3] = fc1_b[tid];
    }
    // ---- phase 0b: phi table (bf16) ----
    {
        const float l2 = log2f(1.0f - DTF);
        for (int t = tid; t < 304; t += 256) {
            ushort row[NB];
            if (t < TS) {
                const float x = exp2f((float)(t + 1) * l2);
                float ps[NB]; float s = 0.0f;
                #pragma unroll
                for (int n = 0; n < NB; ++n) {
                    float d = x - dmp_c[n];
                    float p = __expf(-0.5f * d * d / dmp_s2[n]);
                    ps[n] = p; s += p;
                }
                const float inv = x / s;
                #pragma unroll
                for (int n = 0; n < NB; ++n) row[n] = f2bf(ps[n] * inv);
            } else {
                #pragma unroll
                for (int n = 0; n < NB; ++n) row[n] = 0;
            }
            uint4* dst = (uint4*)(phis + t*NB);
            #pragma unroll
            for (int q4 = 0; q4 < 4; ++q4) {
                union { ushort us[8]; uint4 v; } pk;
                #pragma unroll
                for (int e = 0; e < 8; ++e) pk.us[e] = row[q4*8 + e];
                dst[q4 ^ (t & 3)] = pk.v;   // slot swizzle
            }
        }
    }
    __syncthreads();

    // ---- phase 1: heads (4 waves x 8 batches) ----
    {
        const int r2 = 64 + (j % 6);
        float wr[64], w2[64];
        #pragma unroll
        for (int q = 0; q < 16; ++q) {
            float4 a  = *(const float4*)(wlds + j*64  + ((q ^ (j  & 15)) << 2));
            wr[q*4+0]=a.x; wr[q*4+1]=a.y; wr[q*4+2]=a.z; wr[q*4+3]=a.w;
            float4 b4 = *(const float4*)(wlds + r2*64 + ((q ^ (r2 & 15)) << 2));
            w2[q*4+0]=b4.x; w2[q*4+1]=b4.y; w2[q*4+2]=b4.z; w2[q*4+3]=b4.w;
        }
        const float bias1 = fc2m_b[j];
        const float bias2 = (r2 < 66) ? fc2m_b[r2] : (r2 < 68) ? sig_b[r2-66] : val_b[r2-68];
        const float4 fw = *(const float4*)(f1 + j*4);

        const int bbase = (blockIdx.x << 5) + (wv << 3);
        float sreg = (j < 24) ? state[bbase*3 + j] : 0.0f;

        for (int it = 0; it < 8; ++it) {
            const float s0  = rdlane(sreg, it*3+0);
            const float s1  = rdlane(sreg, it*3+1);
            const float s2v = rdlane(sreg, it*3+2);
            float pre = fmaf(fw.x, s0, fmaf(fw.y, s1, fmaf(fw.z, s2v, fw.w)));
            float e = __expf(2.0f * pre);
            float h = (1.0f - 2.0f/(e + 1.0f)) * 0.1f;   // tanh, overflow-safe
            float a1 = bias1, a1b = 0.0f, a2 = bias2, a2b = 0.0f;
            #pragma unroll
            for (int k = 0; k < 64; k += 2) {
                const float h0 = rdlane(h, k);
                const float h1 = rdlane(h, k+1);
                a1  = fmaf(wr[k],   h0, a1 );
                a1b = fmaf(wr[k+1], h1, a1b);
                a2  = fmaf(w2[k],   h0, a2 );
                a2b = fmaf(w2[k+1], h1, a2b);
            }
            a1 += a1b; a2 += a2b;
            float az = rdlane(a2, 1);                    // raw row 65
            az = fminf(fmaxf(az, 0.5f), 30.0f);
            const float vv0 = rdlane(a2, 4);             // value row 68
            const float vv1 = rdlane(a2, 5);             // value row 69
            const int chp = (wv << 4) + (it << 1);       // local channel pair
            if (j >= 2) wloc[(chp + ((j-2) >> 5))*NB + ((j-2) & 31)] = f2bf(a1);
            else        wloc[(chp + 1)*NB + 30 + j]                  = f2bf(a2);
            if (j == 2 || j == 3)
                sig_out[(bbase + it)*2 + j - 2] = 1.0f / (1.0f + __expf(-a2)) + 0.001f;
            if (j < 2) {
                const float y0 = (j == 0) ? s0 : s1;
                const float vvl = (j == 0) ? vv0 : vv1;
                ppl[chp + j] = make_float4(a1, a1 - y0, az, vvl);
            }
        }
    }
    __syncthreads();

    // ---- phase 2: rollout ----
    const int ch = j & 15;
    const int g  = j >> 4;
    const int chl = (wv << 4) + ch;

    const float4 pp = ppl[chl];                       // {goal, kfac, az, v}
    const float az = pp.z;
    const float Ac = DTF * az * az * 0.25f;
    const float Bc = DTF * az;
    const float Kc = DTF * pp.y;
    const float c0 = Ac * pp.x;                        // all lanes: full state
    float y = pp.x - pp.y;                             // y0
    float z = 0.01f;

    const bf16x8 wb = *(const bf16x8*)(wloc + chl*NB + g*8);
    const ushort* aprow = phis + ch*NB + ((g ^ (ch & 3)) << 3);
    bf16x8 af = *(const bf16x8*)aprow;

    // store-side lane mapping: mloc = j>>2, tq = j&3 -> coalesced 64B/4 lanes
    const int mloc = j >> 2;
    const int m_st = (blockIdx.x << 6) + (wv << 4) + mloc;
    const float fv = ppl[(wv << 4) + mloc].w;
    const float4 vsp = make_float4(fv, fv, fv, fv);
    float* aptr = a_out + m_st*TS + (j & 3)*4;
    float* vptr = v_out + m_st*TS + (j & 3)*4;
    const bool tail_ok = (j & 3) < 3;

    const f32x4 zacc = {0.0f, 0.0f, 0.0f, 0.0f};

    for (int c = 0; c < 19; ++c) {
        f32x4 facc = __builtin_amdgcn_mfma_f32_16x16x32_bf16(af, wb, zacc, 0, 0, 0);
        if (c < 18) af = *(const bf16x8*)(aprow + (c + 1)*16*NB);

        // all-gather F[0..15] across the 4 g-groups (channel-preserving)
        float F[16];
        #pragma unroll
        for (int q = 0; q < 4; ++q) {
            float a = facc[q], b = facc[q];
            asm volatile("v_permlane16_swap_b32 %0, %1" : "+v"(a), "+v"(b));
            // a = even quad of own 32-half, b = odd quad of own 32-half
            float a2 = a, b2 = b;
            asm volatile("v_permlane32_swap_b32 %0, %1" : "+v"(a), "+v"(a2));
            asm volatile("v_permlane32_swap_b32 %0, %1" : "+v"(b), "+v"(b2));
            F[0*4+q] = a; F[1*4+q] = b; F[2*4+q] = a2; F[3*4+q] = b2;
        }

        float avq[4] = {0.f, 0.f, 0.f, 0.f};
        #pragma unroll
        for (int i = 0; i < 16; ++i) {
            const float aval = z * DTF;
            if (g == (i >> 2)) avq[i & 3] = aval;      // own quad for store
            float u = z + c0;
            u = fmaf(Kc, F[i], u);
            u = fmaf(-Bc, z, u);
            z = fmaf(-Ac, y, u);
            y += aval;
        }

        // transpose via LDS (within-wave, in-order DS)
        xt[wv][ch][g] = make_float4(avq[0], avq[1], avq[2], avq[3]);
        if (c < 18 || tail_ok) {
            const float4 s4 = xt[wv][mloc][j & 3];
            *(float4*)aptr = s4;
            *(float4*)vptr = vsp;
        }
        aptr += 16; vptr += 16;
    }
}

extern "C" void kernel_launch(void* const* d_in, const int* in_sizes, int n_in,
                              void* d_out, int out_size, void* d_ws, size_t ws_size,
                              hipStream_t stream) {
    (void)in_sizes; (void)n_in; (void)out_size; (void)d_ws; (void)ws_size;
    const float* state  = (const float*)d_in[0];
    const float* fc1_w  = (const float*)d_in[1];
    const float* fc1_b  = (const float*)d_in[2];
    const float* fc2m_w = (const float*)d_in[3];
    const float* fc2m_b = (const float*)d_in[4];
    const float* sig_w  = (const float*)d_in[5];
    const float* sig_b  = (const float*)d_in[6];
    const float* val_w  = (const float*)d_in[7];
    const float* val_b  = (const float*)d_in[8];
    const float* dmp_c  = (const float*)d_in[9];
    const float* dmp_s2 = (const float*)d_in[10];

    float* out     = (float*)d_out;
    float* a_out   = out;
    float* sig_out = out + A_ELEMS;
    float* v_out   = out + A_ELEMS + NBATCH*2;

    k_fused<<<dim3(512), dim3(256), 0, stream>>>(state, fc1_w, fc1_b, fc2m_w, fc2m_b,
                                                 sig_w, sig_b, val_w, val_b,
                                                 dmp_c, dmp_s2,
                                                 sig_out, a_out, v_out);
}